// Round 1
// baseline (47985.190 us; speedup 1.0000x reference)
//
#include <hip/hip_runtime.h>
#include <cstddef>

// Problem constants
#define BDIM  1024        // batch rows
#define DM    512         // embedding dim
#define CREAL 10000       // dictionary atoms
#define CP    10112       // padded atoms = 79*128
#define KSPL  8           // split-K for the K=CP GEMM
#define KCH   (CP/KSPL)   // 1264, 79 tiles of 16
#define RHOC  5.0f
#define THRC  (0.01f/5.0f)
#define NIT   100
#define NSIT  12

// ---------------- small helpers ----------------

__device__ __forceinline__ float blk_sum256(float v) {
    __shared__ float sb[4];
#pragma unroll
    for (int o = 32; o; o >>= 1) v += __shfl_down(v, o, 64);
    int lane = threadIdx.x & 63, w = threadIdx.x >> 6;
    __syncthreads();               // protect sb from a previous call
    if (lane == 0) sb[w] = v;
    __syncthreads();
    return sb[0] + sb[1] + sb[2] + sb[3];
}

// txt = normalize(text) per row
__global__ __launch_bounds__(256) void knorm_rows(const float* __restrict__ X,
                                                  float* __restrict__ out) {
    int row = blockIdx.x, t = threadIdx.x;
    int off = row * DM + t * 2;
    float2 v = *(const float2*)(X + off);
    float ss = blk_sum256(v.x * v.x + v.y * v.y);
    float inv = 1.0f / fmaxf(sqrtf(ss), 1e-12f);
    float2 o = {v.x * inv, v.y * inv};
    *(float2*)(out + off) = o;
}

// Y = normalize(normalize(image) - mean) per row
__global__ __launch_bounds__(256) void kprep_Y(const float* __restrict__ img,
                                               const float* __restrict__ mean,
                                               float* __restrict__ Y) {
    int row = blockIdx.x, t = threadIdx.x;
    int off = row * DM + t * 2;
    float2 v = *(const float2*)(img + off);
    float ss = blk_sum256(v.x * v.x + v.y * v.y);
    float inv = 1.0f / fmaxf(sqrtf(ss), 1e-12f);
    float2 mm = *(const float2*)(mean + t * 2);
    float tx = v.x * inv - mm.x, ty = v.y * inv - mm.y;
    float ss2 = blk_sum256(tx * tx + ty * ty);
    float inv2 = 1.0f / fmaxf(sqrtf(ss2), 1e-12f);
    float2 o = {tx * inv2, ty * inv2};
    *(float2*)(Y + off) = o;
}

// Dp = D padded with zero rows up to CP
__global__ void kpad_D(const float* __restrict__ D, float* __restrict__ Dp) {
    int i4 = blockIdx.x * 256 + threadIdx.x;   // float4 index, < CP*128
    int c = i4 >> 7;
    float4 v = {0.f, 0.f, 0.f, 0.f};
    if (c < CREAL) v = *(const float4*)(D + (size_t)i4 * 4);
    *(float4*)(Dp + (size_t)i4 * 4) = v;
}

// G = Dp^T Dp + rho*I   (64x64 tiles, K=CP)
__global__ __launch_bounds__(256) void kgemm_G(const float* __restrict__ Dp,
                                               float* __restrict__ G) {
    __shared__ float As[32][68];
    __shared__ float Bs[32][68];
    int tid = threadIdx.x;
    int j0 = blockIdx.x * 64, i0 = blockIdx.y * 64;
    int tn = (tid & 15) * 4, tm = (tid >> 4) * 4;
    float acc[4][4];
#pragma unroll
    for (int i = 0; i < 4; i++)
#pragma unroll
        for (int j = 0; j < 4; j++) acc[i][j] = 0.f;
    for (int k0 = 0; k0 < CP; k0 += 32) {
        __syncthreads();
#pragma unroll
        for (int p = 0; p < 2; ++p) {
            int idx = tid + p * 256;
            int r = idx >> 4, cv = (idx & 15) << 2;
            *(float4*)&As[r][cv] = *(const float4*)(Dp + (size_t)(k0 + r) * DM + i0 + cv);
            *(float4*)&Bs[r][cv] = *(const float4*)(Dp + (size_t)(k0 + r) * DM + j0 + cv);
        }
        __syncthreads();
#pragma unroll
        for (int k = 0; k < 32; ++k) {
            float4 a4 = *(const float4*)&As[k][tm];
            float4 b4 = *(const float4*)&Bs[k][tn];
            float af[4] = {a4.x, a4.y, a4.z, a4.w};
            float bf[4] = {b4.x, b4.y, b4.z, b4.w};
#pragma unroll
            for (int i = 0; i < 4; i++)
#pragma unroll
                for (int j = 0; j < 4; j++) acc[i][j] = fmaf(af[i], bf[j], acc[i][j]);
        }
    }
#pragma unroll
    for (int i = 0; i < 4; i++)
#pragma unroll
        for (int j = 0; j < 4; j++) {
            int gi = i0 + tm + i, gj = j0 + tn + j;
            G[gi * DM + gj] = acc[i][j] + ((gi == gj) ? RHOC : 0.f);
        }
}

// gmax = max_i sum_j |G_ij|  (Gershgorin bound on lambda_max)
__global__ void krow_abssum(const float* __restrict__ G, float* __restrict__ gmax) {
    int row = blockIdx.x, t = threadIdx.x;   // 64 threads = 1 wave
    float s = 0.f;
    for (int j = t; j < DM; j += 64) s += fabsf(G[row * DM + j]);
#pragma unroll
    for (int o = 32; o; o >>= 1) s += __shfl_down(s, o, 64);
    if (t == 0) atomicMax((int*)gmax, __float_as_int(s));   // valid for nonneg floats
}

__global__ void kinit_X0(const float* __restrict__ gmax, float* __restrict__ X) {
    int idx = blockIdx.x * 256 + threadIdx.x;   // < DM*DM
    int i = idx >> 9, j = idx & 511;
    X[idx] = (i == j) ? (1.0f / gmax[0]) : 0.0f;
}

// T = G @ X   (512^3 NN GEMM, 64x64 tiles)
__global__ __launch_bounds__(256) void kgemm_ns_T(const float* __restrict__ G,
                                                  const float* __restrict__ X,
                                                  float* __restrict__ T) {
    __shared__ float As[32][68];
    __shared__ float Bs[32][68];
    int tid = threadIdx.x;
    int n0 = blockIdx.x * 64, m0 = blockIdx.y * 64;
    int tn = (tid & 15) * 4, tm = (tid >> 4) * 4;
    float acc[4][4];
#pragma unroll
    for (int i = 0; i < 4; i++)
#pragma unroll
        for (int j = 0; j < 4; j++) acc[i][j] = 0.f;
    for (int k0 = 0; k0 < DM; k0 += 32) {
        __syncthreads();
#pragma unroll
        for (int p = 0; p < 2; ++p) {
            int idx = tid + p * 256;
            {   // A (transposed store): rows m0..+63, k 32
                int row = idx >> 3, kv = (idx & 7) << 2;
                float4 v = *(const float4*)(G + (m0 + row) * DM + k0 + kv);
                As[kv + 0][row] = v.x; As[kv + 1][row] = v.y;
                As[kv + 2][row] = v.z; As[kv + 3][row] = v.w;
            }
            {   // B as-is
                int r = idx >> 4, cv = (idx & 15) << 2;
                *(float4*)&Bs[r][cv] = *(const float4*)(X + (k0 + r) * DM + n0 + cv);
            }
        }
        __syncthreads();
#pragma unroll
        for (int k = 0; k < 32; ++k) {
            float4 a4 = *(const float4*)&As[k][tm];
            float4 b4 = *(const float4*)&Bs[k][tn];
            float af[4] = {a4.x, a4.y, a4.z, a4.w};
            float bf[4] = {b4.x, b4.y, b4.z, b4.w};
#pragma unroll
            for (int i = 0; i < 4; i++)
#pragma unroll
                for (int j = 0; j < 4; j++) acc[i][j] = fmaf(af[i], bf[j], acc[i][j]);
        }
    }
#pragma unroll
    for (int i = 0; i < 4; i++) {
        float4 o = {acc[i][0], acc[i][1], acc[i][2], acc[i][3]};
        *(float4*)(T + (m0 + tm + i) * DM + n0 + tn) = o;
    }
}

// Xn = 2*Xo - Xo @ T  (Newton-Schulz step)
__global__ __launch_bounds__(256) void kgemm_ns_X(const float* __restrict__ Xo,
                                                  const float* __restrict__ T,
                                                  float* __restrict__ Xn) {
    __shared__ float As[32][68];
    __shared__ float Bs[32][68];
    int tid = threadIdx.x;
    int n0 = blockIdx.x * 64, m0 = blockIdx.y * 64;
    int tn = (tid & 15) * 4, tm = (tid >> 4) * 4;
    float acc[4][4];
#pragma unroll
    for (int i = 0; i < 4; i++)
#pragma unroll
        for (int j = 0; j < 4; j++) acc[i][j] = 0.f;
    for (int k0 = 0; k0 < DM; k0 += 32) {
        __syncthreads();
#pragma unroll
        for (int p = 0; p < 2; ++p) {
            int idx = tid + p * 256;
            {
                int row = idx >> 3, kv = (idx & 7) << 2;
                float4 v = *(const float4*)(Xo + (m0 + row) * DM + k0 + kv);
                As[kv + 0][row] = v.x; As[kv + 1][row] = v.y;
                As[kv + 2][row] = v.z; As[kv + 3][row] = v.w;
            }
            {
                int r = idx >> 4, cv = (idx & 15) << 2;
                *(float4*)&Bs[r][cv] = *(const float4*)(T + (k0 + r) * DM + n0 + cv);
            }
        }
        __syncthreads();
#pragma unroll
        for (int k = 0; k < 32; ++k) {
            float4 a4 = *(const float4*)&As[k][tm];
            float4 b4 = *(const float4*)&Bs[k][tn];
            float af[4] = {a4.x, a4.y, a4.z, a4.w};
            float bf[4] = {b4.x, b4.y, b4.z, b4.w};
#pragma unroll
            for (int i = 0; i < 4; i++)
#pragma unroll
                for (int j = 0; j < 4; j++) acc[i][j] = fmaf(af[i], bf[j], acc[i][j]);
        }
    }
#pragma unroll
    for (int i = 0; i < 4; i++) {
        int base = (m0 + tm + i) * DM + n0 + tn;
        float4 xo = *(const float4*)(Xo + base);
        float4 o = {2.f * xo.x - acc[i][0], 2.f * xo.y - acc[i][1],
                    2.f * xo.z - acc[i][2], 2.f * xo.w - acc[i][3]};
        *(float4*)(Xn + base) = o;
    }
}

// NT GEMM: out[M=1024, N=CP] over K=DM. A[M,DM], Bm[CP,DM] both K-contiguous.
// MODE 0: aBuf = acc/rho        (a = Y @ Dp^T / rho)
// MODE 1: P   = aBuf + relu(P-thr) - acc   (fused ADMM update; acc = T @ Dp^T)
template <int MODE>
__global__ __launch_bounds__(256) void kgemm_nt128(const float* __restrict__ A,
                                                   const float* __restrict__ Bm,
                                                   float* __restrict__ aBuf,
                                                   float* __restrict__ P) {
    __shared__ float As[32][132];
    __shared__ float Bs[32][132];
    const int tid = threadIdx.x;
    const int n0 = blockIdx.x * 128;
    const int m0 = blockIdx.y * 128;
    const int tn = (tid & 15) * 8;
    const int tm = (tid >> 4) * 8;
    float acc[8][8];
#pragma unroll
    for (int i = 0; i < 8; i++)
#pragma unroll
        for (int j = 0; j < 8; j++) acc[i][j] = 0.f;

    for (int k0 = 0; k0 < DM; k0 += 32) {
        __syncthreads();
#pragma unroll
        for (int p = 0; p < 4; ++p) {
            int idx = tid + p * 256;
            int row = idx >> 3;
            int kv = (idx & 7) << 2;
            float4 va = *(const float4*)(A + (m0 + row) * DM + k0 + kv);
            As[kv + 0][row] = va.x; As[kv + 1][row] = va.y;
            As[kv + 2][row] = va.z; As[kv + 3][row] = va.w;
            float4 vb = *(const float4*)(Bm + (size_t)(n0 + row) * DM + k0 + kv);
            Bs[kv + 0][row] = vb.x; Bs[kv + 1][row] = vb.y;
            Bs[kv + 2][row] = vb.z; Bs[kv + 3][row] = vb.w;
        }
        __syncthreads();
#pragma unroll
        for (int k = 0; k < 32; ++k) {
            float af[8], bf[8];
            *(float4*)&af[0] = *(const float4*)&As[k][tm];
            *(float4*)&af[4] = *(const float4*)&As[k][tm + 4];
            *(float4*)&bf[0] = *(const float4*)&Bs[k][tn];
            *(float4*)&bf[4] = *(const float4*)&Bs[k][tn + 4];
#pragma unroll
            for (int i = 0; i < 8; i++)
#pragma unroll
                for (int j = 0; j < 8; j++) acc[i][j] = fmaf(af[i], bf[j], acc[i][j]);
        }
    }
#pragma unroll
    for (int i = 0; i < 8; i++) {
        int base = (m0 + tm + i) * CP + n0 + tn;
        if (MODE == 0) {
            float4 o0 = {acc[i][0] * 0.2f, acc[i][1] * 0.2f, acc[i][2] * 0.2f, acc[i][3] * 0.2f};
            float4 o1 = {acc[i][4] * 0.2f, acc[i][5] * 0.2f, acc[i][6] * 0.2f, acc[i][7] * 0.2f};
            *(float4*)(aBuf + base) = o0;
            *(float4*)(aBuf + base + 4) = o1;
        } else {
            float4 av0 = *(const float4*)(aBuf + base);
            float4 av1 = *(const float4*)(aBuf + base + 4);
            float4 pv0 = *(const float4*)(P + base);
            float4 pv1 = *(const float4*)(P + base + 4);
            float4 o0, o1;
            o0.x = av0.x + fmaxf(pv0.x - THRC, 0.f) - acc[i][0];
            o0.y = av0.y + fmaxf(pv0.y - THRC, 0.f) - acc[i][1];
            o0.z = av0.z + fmaxf(pv0.z - THRC, 0.f) - acc[i][2];
            o0.w = av0.w + fmaxf(pv0.w - THRC, 0.f) - acc[i][3];
            o1.x = av1.x + fmaxf(pv1.x - THRC, 0.f) - acc[i][4];
            o1.y = av1.y + fmaxf(pv1.y - THRC, 0.f) - acc[i][5];
            o1.z = av1.z + fmaxf(pv1.z - THRC, 0.f) - acc[i][6];
            o1.w = av1.w + fmaxf(pv1.w - THRC, 0.f) - acc[i][7];
            *(float4*)(P + base) = o0;
            *(float4*)(P + base + 4) = o1;
        }
    }
}

// NN GEMM split-K: Qout[ks][M=1024, N=DM], K-chunk of CP.
// A element built on the fly from (a, P):
//   MODE 0: V = a + ((P>thr) ? P-2thr : -P)     (= a + z - u)
//   MODE 1: V = relu(P - thr)                    (= z, for final recon)
template <int MODE>
__global__ __launch_bounds__(256) void kgemm_nn128(const float* __restrict__ aBuf,
                                                   const float* __restrict__ P,
                                                   const float* __restrict__ Dp,
                                                   float* __restrict__ Qout) {
    __shared__ float As[16][132];
    __shared__ float Bs[16][132];
    const int tid = threadIdx.x;
    const int n0 = blockIdx.x * 128;
    const int m0 = blockIdx.y * 128;
    const int ks = blockIdx.z;
    const int tn = (tid & 15) * 8;
    const int tm = (tid >> 4) * 8;
    float acc[8][8];
#pragma unroll
    for (int i = 0; i < 8; i++)
#pragma unroll
        for (int j = 0; j < 8; j++) acc[i][j] = 0.f;

    const int kbeg = ks * KCH;
    const int kend = kbeg + KCH;
    for (int k0 = kbeg; k0 < kend; k0 += 16) {
        __syncthreads();
#pragma unroll
        for (int p = 0; p < 2; ++p) {
            int idx = tid + p * 256;
            {   // A tile 128 x 16, transposed store
                int row = idx >> 2;
                int kv = (idx & 3) << 2;
                int off = (m0 + row) * CP + k0 + kv;
                float4 pv = *(const float4*)(P + off);
                float4 v;
                if (MODE == 0) {
                    float4 av = *(const float4*)(aBuf + off);
                    v.x = av.x + ((pv.x > THRC) ? pv.x - 2.f * THRC : -pv.x);
                    v.y = av.y + ((pv.y > THRC) ? pv.y - 2.f * THRC : -pv.y);
                    v.z = av.z + ((pv.z > THRC) ? pv.z - 2.f * THRC : -pv.z);
                    v.w = av.w + ((pv.w > THRC) ? pv.w - 2.f * THRC : -pv.w);
                } else {
                    v.x = fmaxf(pv.x - THRC, 0.f);
                    v.y = fmaxf(pv.y - THRC, 0.f);
                    v.z = fmaxf(pv.z - THRC, 0.f);
                    v.w = fmaxf(pv.w - THRC, 0.f);
                }
                As[kv + 0][row] = v.x; As[kv + 1][row] = v.y;
                As[kv + 2][row] = v.z; As[kv + 3][row] = v.w;
            }
            {   // B tile 16 x 128, as-is
                int r = idx >> 5;
                int cv = (idx & 31) << 2;
                *(float4*)&Bs[r][cv] = *(const float4*)(Dp + (size_t)(k0 + r) * DM + n0 + cv);
            }
        }
        __syncthreads();
#pragma unroll
        for (int k = 0; k < 16; ++k) {
            float af[8], bf[8];
            *(float4*)&af[0] = *(const float4*)&As[k][tm];
            *(float4*)&af[4] = *(const float4*)&As[k][tm + 4];
            *(float4*)&bf[0] = *(const float4*)&Bs[k][tn];
            *(float4*)&bf[4] = *(const float4*)&Bs[k][tn + 4];
#pragma unroll
            for (int i = 0; i < 8; i++)
#pragma unroll
                for (int j = 0; j < 8; j++) acc[i][j] = fmaf(af[i], bf[j], acc[i][j]);
        }
    }
    float* out = Qout + (size_t)ks * (BDIM * DM);
#pragma unroll
    for (int i = 0; i < 8; i++) {
        int base = (m0 + tm + i) * DM + n0 + tn;
        float4 o0 = {acc[i][0], acc[i][1], acc[i][2], acc[i][3]};
        float4 o1 = {acc[i][4], acc[i][5], acc[i][6], acc[i][7]};
        *(float4*)(out + base) = o0;
        *(float4*)(out + base + 4) = o1;
    }
}

// T = (sum_s Q8[s]) @ Ginv   [1024,512]x[512,512]; 64x64 tiles
__global__ __launch_bounds__(256) void kgemm_sumq(const float* __restrict__ Q8,
                                                  const float* __restrict__ Gi,
                                                  float* __restrict__ T) {
    __shared__ float As[32][68];
    __shared__ float Bs[32][68];
    int tid = threadIdx.x;
    int n0 = blockIdx.x * 64, m0 = blockIdx.y * 64;
    int tn = (tid & 15) * 4, tm = (tid >> 4) * 4;
    float acc[4][4];
#pragma unroll
    for (int i = 0; i < 4; i++)
#pragma unroll
        for (int j = 0; j < 4; j++) acc[i][j] = 0.f;
    for (int k0 = 0; k0 < DM; k0 += 32) {
        __syncthreads();
#pragma unroll
        for (int p = 0; p < 2; ++p) {
            int idx = tid + p * 256;
            {   // A: sum 8 partials, transposed store
                int row = idx >> 3, kv = (idx & 7) << 2;
                int off = (m0 + row) * DM + k0 + kv;
                float4 s = *(const float4*)(Q8 + off);
#pragma unroll
                for (int q = 1; q < KSPL; q++) {
                    float4 t4 = *(const float4*)(Q8 + (size_t)q * (BDIM * DM) + off);
                    s.x += t4.x; s.y += t4.y; s.z += t4.z; s.w += t4.w;
                }
                As[kv + 0][row] = s.x; As[kv + 1][row] = s.y;
                As[kv + 2][row] = s.z; As[kv + 3][row] = s.w;
            }
            {
                int r = idx >> 4, cv = (idx & 15) << 2;
                *(float4*)&Bs[r][cv] = *(const float4*)(Gi + (k0 + r) * DM + n0 + cv);
            }
        }
        __syncthreads();
#pragma unroll
        for (int k = 0; k < 32; ++k) {
            float4 a4 = *(const float4*)&As[k][tm];
            float4 b4 = *(const float4*)&Bs[k][tn];
            float af[4] = {a4.x, a4.y, a4.z, a4.w};
            float bf[4] = {b4.x, b4.y, b4.z, b4.w};
#pragma unroll
            for (int i = 0; i < 4; i++)
#pragma unroll
                for (int j = 0; j < 4; j++) acc[i][j] = fmaf(af[i], bf[j], acc[i][j]);
        }
    }
#pragma unroll
    for (int i = 0; i < 4; i++) {
        float4 o = {acc[i][0], acc[i][1], acc[i][2], acc[i][3]};
        *(float4*)(T + (m0 + tm + i) * DM + n0 + tn) = o;
    }
}

// final: recon = normalize(normalize(sum_s R8[s]) + mean)
__global__ __launch_bounds__(256) void kfinal(const float* __restrict__ R8,
                                              const float* __restrict__ mean,
                                              float* __restrict__ out) {
    int row = blockIdx.x, t = threadIdx.x;
    int off = row * DM + t * 2;
    float rx = 0.f, ry = 0.f;
#pragma unroll
    for (int q = 0; q < KSPL; q++) {
        float2 v = *(const float2*)(R8 + (size_t)q * (BDIM * DM) + off);
        rx += v.x; ry += v.y;
    }
    float ss = blk_sum256(rx * rx + ry * ry);
    float inv = 1.0f / fmaxf(sqrtf(ss), 1e-12f);
    rx *= inv; ry *= inv;
    float2 mm = *(const float2*)(mean + t * 2);
    rx += mm.x; ry += mm.y;
    float ss2 = blk_sum256(rx * rx + ry * ry);
    float inv2 = 1.0f / fmaxf(sqrtf(ss2), 1e-12f);
    float2 o = {rx * inv2, ry * inv2};
    *(float2*)(out + off) = o;
}

extern "C" void kernel_launch(void* const* d_in, const int* in_sizes, int n_in,
                              void* d_out, int out_size, void* d_ws, size_t ws_size,
                              hipStream_t stream) {
    const float* image = (const float*)d_in[0];
    const float* text  = (const float*)d_in[1];
    const float* mean  = (const float*)d_in[2];
    const float* D     = (const float*)d_in[3];
    float* out = (float*)d_out;
    float* ws = (float*)d_ws;

    // workspace layout (floats); total ~32.2M floats ~ 129 MB
    float* Y    = ws;                           // 1024*512
    float* Dp   = Y + (size_t)BDIM * DM;        // CP*512
    float* G    = Dp + (size_t)CP * DM;         // 512*512
    float* Xa   = G + DM * DM;
    float* Xb   = Xa + DM * DM;
    float* Tns  = Xb + DM * DM;
    float* aB   = Tns + DM * DM;                // 1024*CP
    float* P    = aB + (size_t)BDIM * CP;       // 1024*CP
    float* Q8   = P + (size_t)BDIM * CP;        // 8*1024*512
    float* Tm   = Q8 + (size_t)KSPL * BDIM * DM;// 1024*512
    float* gmax = Tm + (size_t)BDIM * DM;       // 1

    // text branch + Y prep + padded dictionary
    knorm_rows<<<BDIM, 256, 0, stream>>>(text, out + (size_t)BDIM * DM);
    kprep_Y<<<BDIM, 256, 0, stream>>>(image, mean, Y);
    kpad_D<<<CP / 2, 256, 0, stream>>>(D, Dp);

    // G = Dp^T Dp + rho I ; Ginv by Newton-Schulz
    kgemm_G<<<dim3(8, 8), 256, 0, stream>>>(Dp, G);
    hipMemsetAsync(gmax, 0, 4, stream);
    krow_abssum<<<DM, 64, 0, stream>>>(G, gmax);
    kinit_X0<<<DM * DM / 256, 256, 0, stream>>>(gmax, Xa);
    float* xc = Xa;
    float* xn = Xb;
    for (int it = 0; it < NSIT; ++it) {
        kgemm_ns_T<<<dim3(8, 8), 256, 0, stream>>>(G, xc, Tns);
        kgemm_ns_X<<<dim3(8, 8), 256, 0, stream>>>(xc, Tns, xn);
        float* tmp = xc; xc = xn; xn = tmp;
    }
    float* Ginv = xc;

    // a = Y @ Dp^T / rho ; P = 0
    kgemm_nt128<0><<<dim3(CP / 128, BDIM / 128), 256, 0, stream>>>(Y, Dp, aB, nullptr);
    hipMemsetAsync(P, 0, (size_t)BDIM * CP * sizeof(float), stream);

    // ADMM main loop
    for (int it = 0; it < NIT; ++it) {
        kgemm_nn128<0><<<dim3(DM / 128, BDIM / 128, KSPL), 256, 0, stream>>>(aB, P, Dp, Q8);
        kgemm_sumq<<<dim3(DM / 64, BDIM / 64), 256, 0, stream>>>(Q8, Ginv, Tm);
        kgemm_nt128<1><<<dim3(CP / 128, BDIM / 128), 256, 0, stream>>>(Tm, Dp, aB, P);
    }

    // recon = z @ D, then double-normalize with mean
    kgemm_nn128<1><<<dim3(DM / 128, BDIM / 128, KSPL), 256, 0, stream>>>(P, P, Dp, Q8);
    kfinal<<<BDIM, 256, 0, stream>>>(Q8, mean, out);
}

// Round 6
// 21680.508 us; speedup vs baseline: 2.2133x; 2.2133x over previous
//
#include <hip/hip_runtime.h>
#include <cstddef>
#include <cstdint>

// Problem constants
#define BDIM  1024        // batch rows
#define DM    512         // embedding dim
#define CREAL 10000       // dictionary atoms
#define CP    10112       // padded atoms = 79*128 = 158*64 = 316*32
#define KSPL  8           // split-K chunks for GEMM1 (atomic accumulation)
#define RHOC  5.0f
#define THRC  (0.01f/5.0f)
#define NIT   100
#define NSIT  12

typedef unsigned short u16;
typedef u16   u16x8 __attribute__((ext_vector_type(8)));
typedef u16   u16x4 __attribute__((ext_vector_type(4)));
typedef short s16x8 __attribute__((ext_vector_type(8)));
typedef float f32x4 __attribute__((ext_vector_type(4)));
typedef _Float16 f16x8 __attribute__((ext_vector_type(8)));

// ---------------- helpers ----------------

__device__ __forceinline__ u16 f2bf(float f) {   // RNE float->bf16
    unsigned u = __float_as_uint(f);
    u += 0x7FFFu + ((u >> 16) & 1u);
    return (u16)(u >> 16);
}
__device__ __forceinline__ float bf2f(u16 h) {
    return __uint_as_float(((unsigned)h) << 16);
}

__device__ __forceinline__ float blk_sum256(float v) {
    __shared__ float sb[4];
#pragma unroll
    for (int o = 32; o; o >>= 1) v += __shfl_down(v, o, 64);
    int lane = threadIdx.x & 63, w = threadIdx.x >> 6;
    __syncthreads();
    if (lane == 0) sb[w] = v;
    __syncthreads();
    return sb[0] + sb[1] + sb[2] + sb[3];
}

// txt = normalize(text) per row
__global__ __launch_bounds__(256) void knorm_rows(const float* __restrict__ X,
                                                  float* __restrict__ out) {
    int row = blockIdx.x, t = threadIdx.x;
    int off = row * DM + t * 2;
    float2 v = *(const float2*)(X + off);
    float ss = blk_sum256(v.x * v.x + v.y * v.y);
    float inv = 1.0f / fmaxf(sqrtf(ss), 1e-12f);
    float2 o = {v.x * inv, v.y * inv};
    *(float2*)(out + off) = o;
}

// Y = normalize(normalize(image) - mean) per row
__global__ __launch_bounds__(256) void kprep_Y(const float* __restrict__ img,
                                               const float* __restrict__ mean,
                                               float* __restrict__ Y) {
    int row = blockIdx.x, t = threadIdx.x;
    int off = row * DM + t * 2;
    float2 v = *(const float2*)(img + off);
    float ss = blk_sum256(v.x * v.x + v.y * v.y);
    float inv = 1.0f / fmaxf(sqrtf(ss), 1e-12f);
    float2 mm = *(const float2*)(mean + t * 2);
    float tx = v.x * inv - mm.x, ty = v.y * inv - mm.y;
    float ss2 = blk_sum256(tx * tx + ty * ty);
    float inv2 = 1.0f / fmaxf(sqrtf(ss2), 1e-12f);
    float2 o = {tx * inv2, ty * inv2};
    *(float2*)(Y + off) = o;
}

// transpose (+zero-pad rows>=Rvalid), split to bf16 planes (pair, optional 3rd),
// optional fp32 out = reconstructed PAIR (h0+h1) so the pair is EXACT downstream.
__global__ __launch_bounds__(256) void ktrs(const float* __restrict__ in,
                                            float* __restrict__ out32,
                                            u16* __restrict__ o0,
                                            u16* __restrict__ o1,
                                            u16* __restrict__ o2,
                                            int Rvalid, int Cin, int Rout) {
    __shared__ float tile[64][65];
    int r0 = blockIdx.x * 64;   // rows of in  (cols of out)
    int c0 = blockIdx.y * 64;   // cols of in  (rows of out)
    int t = threadIdx.x;
    int ri = r0 + (t >> 2);
    int cc = (t & 3) * 16;
#pragma unroll
    for (int q = 0; q < 4; ++q) {
        float4 v = {0.f, 0.f, 0.f, 0.f};
        if (ri < Rvalid) v = *(const float4*)(in + (size_t)ri * Cin + c0 + cc + q * 4);
        *(float4*)&tile[t >> 2][cc + q * 4] = v;
    }
    __syncthreads();
    int oc = c0 + (t >> 2);            // out row
    int orr = r0 + (t & 3) * 16;       // out col base
#pragma unroll
    for (int q = 0; q < 16; ++q) {
        float v = tile[(t & 3) * 16 + q][t >> 2];
        size_t idx = (size_t)oc * Rout + orr + q;
        u16 h0 = f2bf(v);
        float r = v - bf2f(h0);
        u16 h1 = f2bf(r);
        o0[idx] = h0;
        o1[idx] = h1;
        if (o2) o2[idx] = f2bf(r - bf2f(h1));
        if (out32) out32[idx] = bf2f(h0) + bf2f(h1);
    }
}

// G = Dt*Dt^T + rho I  (Dt [512][CP] fp32; 64x64 tiles, K=CP)
__global__ __launch_bounds__(256) void kG(const float* __restrict__ Dt,
                                          float* __restrict__ G) {
    __shared__ float As[32][68];
    __shared__ float Bs[32][68];
    int tid = threadIdx.x;
    int j0 = blockIdx.x * 64, i0 = blockIdx.y * 64;
    int tn = (tid & 15) * 4, tm = (tid >> 4) * 4;
    float acc[4][4];
#pragma unroll
    for (int i = 0; i < 4; i++)
#pragma unroll
        for (int j = 0; j < 4; j++) acc[i][j] = 0.f;
    for (int k0 = 0; k0 < CP; k0 += 32) {
        __syncthreads();
#pragma unroll
        for (int p = 0; p < 2; ++p) {
            int idx = tid + p * 256;
            int row = idx >> 3, kv = (idx & 7) << 2;
            float4 va = *(const float4*)(Dt + (size_t)(i0 + row) * CP + k0 + kv);
            As[kv + 0][row] = va.x; As[kv + 1][row] = va.y;
            As[kv + 2][row] = va.z; As[kv + 3][row] = va.w;
            float4 vb = *(const float4*)(Dt + (size_t)(j0 + row) * CP + k0 + kv);
            Bs[kv + 0][row] = vb.x; Bs[kv + 1][row] = vb.y;
            Bs[kv + 2][row] = vb.z; Bs[kv + 3][row] = vb.w;
        }
        __syncthreads();
#pragma unroll
        for (int k = 0; k < 32; ++k) {
            float4 a4 = *(const float4*)&As[k][tm];
            float4 b4 = *(const float4*)&Bs[k][tn];
            float af[4] = {a4.x, a4.y, a4.z, a4.w};
            float bf[4] = {b4.x, b4.y, b4.z, b4.w};
#pragma unroll
            for (int i = 0; i < 4; i++)
#pragma unroll
                for (int j = 0; j < 4; j++) acc[i][j] = fmaf(af[i], bf[j], acc[i][j]);
        }
    }
#pragma unroll
    for (int i = 0; i < 4; i++)
#pragma unroll
        for (int j = 0; j < 4; j++) {
            int gi = i0 + tm + i, gj = j0 + tn + j;
            G[gi * DM + gj] = acc[i][j] + ((gi == gj) ? RHOC : 0.f);
        }
}

__global__ void krow_abssum(const float* __restrict__ G, float* __restrict__ gmax) {
    int row = blockIdx.x, t = threadIdx.x;   // 64 threads = 1 wave
    float s = 0.f;
    for (int j = t; j < DM; j += 64) s += fabsf(G[row * DM + j]);
#pragma unroll
    for (int o = 32; o; o >>= 1) s += __shfl_down(s, o, 64);
    if (t == 0) atomicMax((int*)gmax, __float_as_int(s));
}

__global__ void kinit_X0(const float* __restrict__ gmax, float* __restrict__ X) {
    int idx = blockIdx.x * 256 + threadIdx.x;
    int i = idx >> 9, j = idx & 511;
    X[idx] = (i == j) ? (1.0f / gmax[0]) : 0.0f;
}

// T = G @ X (512^3 NN, 64x64 tiles)
__global__ __launch_bounds__(256) void kgemm_ns_T(const float* __restrict__ G,
                                                  const float* __restrict__ X,
                                                  float* __restrict__ T) {
    __shared__ float As[32][68];
    __shared__ float Bs[32][68];
    int tid = threadIdx.x;
    int n0 = blockIdx.x * 64, m0 = blockIdx.y * 64;
    int tn = (tid & 15) * 4, tm = (tid >> 4) * 4;
    float acc[4][4];
#pragma unroll
    for (int i = 0; i < 4; i++)
#pragma unroll
        for (int j = 0; j < 4; j++) acc[i][j] = 0.f;
    for (int k0 = 0; k0 < DM; k0 += 32) {
        __syncthreads();
#pragma unroll
        for (int p = 0; p < 2; ++p) {
            int idx = tid + p * 256;
            {
                int row = idx >> 3, kv = (idx & 7) << 2;
                float4 v = *(const float4*)(G + (m0 + row) * DM + k0 + kv);
                As[kv + 0][row] = v.x; As[kv + 1][row] = v.y;
                As[kv + 2][row] = v.z; As[kv + 3][row] = v.w;
            }
            {
                int r = idx >> 4, cv = (idx & 15) << 2;
                *(float4*)&Bs[r][cv] = *(const float4*)(X + (k0 + r) * DM + n0 + cv);
            }
        }
        __syncthreads();
#pragma unroll
        for (int k = 0; k < 32; ++k) {
            float4 a4 = *(const float4*)&As[k][tm];
            float4 b4 = *(const float4*)&Bs[k][tn];
            float af[4] = {a4.x, a4.y, a4.z, a4.w};
            float bf[4] = {b4.x, b4.y, b4.z, b4.w};
#pragma unroll
            for (int i = 0; i < 4; i++)
#pragma unroll
                for (int j = 0; j < 4; j++) acc[i][j] = fmaf(af[i], bf[j], acc[i][j]);
        }
    }
#pragma unroll
    for (int i = 0; i < 4; i++) {
        float4 o = {acc[i][0], acc[i][1], acc[i][2], acc[i][3]};
        *(float4*)(T + (m0 + tm + i) * DM + n0 + tn) = o;
    }
}

// Xn = 2*Xo - Xo @ T
__global__ __launch_bounds__(256) void kgemm_ns_X(const float* __restrict__ Xo,
                                                  const float* __restrict__ T,
                                                  float* __restrict__ Xn) {
    __shared__ float As[32][68];
    __shared__ float Bs[32][68];
    int tid = threadIdx.x;
    int n0 = blockIdx.x * 64, m0 = blockIdx.y * 64;
    int tn = (tid & 15) * 4, tm = (tid >> 4) * 4;
    float acc[4][4];
#pragma unroll
    for (int i = 0; i < 4; i++)
#pragma unroll
        for (int j = 0; j < 4; j++) acc[i][j] = 0.f;
    for (int k0 = 0; k0 < DM; k0 += 32) {
        __syncthreads();
#pragma unroll
        for (int p = 0; p < 2; ++p) {
            int idx = tid + p * 256;
            {
                int row = idx >> 3, kv = (idx & 7) << 2;
                float4 v = *(const float4*)(Xo + (m0 + row) * DM + k0 + kv);
                As[kv + 0][row] = v.x; As[kv + 1][row] = v.y;
                As[kv + 2][row] = v.z; As[kv + 3][row] = v.w;
            }
            {
                int r = idx >> 4, cv = (idx & 15) << 2;
                *(float4*)&Bs[r][cv] = *(const float4*)(T + (k0 + r) * DM + n0 + cv);
            }
        }
        __syncthreads();
#pragma unroll
        for (int k = 0; k < 32; ++k) {
            float4 a4 = *(const float4*)&As[k][tm];
            float4 b4 = *(const float4*)&Bs[k][tn];
            float af[4] = {a4.x, a4.y, a4.z, a4.w};
            float bf[4] = {b4.x, b4.y, b4.z, b4.w};
#pragma unroll
            for (int i = 0; i < 4; i++)
#pragma unroll
                for (int j = 0; j < 4; j++) acc[i][j] = fmaf(af[i], bf[j], acc[i][j]);
        }
    }
#pragma unroll
    for (int i = 0; i < 4; i++) {
        int base = (m0 + tm + i) * DM + n0 + tn;
        float4 xo = *(const float4*)(Xo + base);
        float4 o = {2.f * xo.x - acc[i][0], 2.f * xo.y - acc[i][1],
                    2.f * xo.z - acc[i][2], 2.f * xo.w - acc[i][3]};
        *(float4*)(Xn + base) = o;
    }
}

// NN fp32: out[M][CP] = A[M][512] @ B[512][CP]
// MODE 0: store fp32. MODE 1: store a = acc*0.2 as scaled fp16 (x64).
template <int MODE>
__global__ __launch_bounds__(256) void kgemm_nn64(const float* __restrict__ A,
                                                  const float* __restrict__ B,
                                                  float* __restrict__ out32,
                                                  _Float16* __restrict__ oA) {
    __shared__ float As[32][68];
    __shared__ float Bs[32][68];
    int tid = threadIdx.x;
    int n0 = blockIdx.x * 64, m0 = blockIdx.y * 64;
    int tn = (tid & 15) * 4, tm = (tid >> 4) * 4;
    float acc[4][4];
#pragma unroll
    for (int i = 0; i < 4; i++)
#pragma unroll
        for (int j = 0; j < 4; j++) acc[i][j] = 0.f;
    for (int k0 = 0; k0 < DM; k0 += 32) {
        __syncthreads();
#pragma unroll
        for (int p = 0; p < 2; ++p) {
            int idx = tid + p * 256;
            {
                int row = idx >> 3, kv = (idx & 7) << 2;
                float4 v = *(const float4*)(A + (size_t)(m0 + row) * DM + k0 + kv);
                As[kv + 0][row] = v.x; As[kv + 1][row] = v.y;
                As[kv + 2][row] = v.z; As[kv + 3][row] = v.w;
            }
            {
                int r = idx >> 4, cv = (idx & 15) << 2;
                *(float4*)&Bs[r][cv] = *(const float4*)(B + (size_t)(k0 + r) * CP + n0 + cv);
            }
        }
        __syncthreads();
#pragma unroll
        for (int k = 0; k < 32; ++k) {
            float4 a4 = *(const float4*)&As[k][tm];
            float4 b4 = *(const float4*)&Bs[k][tn];
            float af[4] = {a4.x, a4.y, a4.z, a4.w};
            float bf[4] = {b4.x, b4.y, b4.z, b4.w};
#pragma unroll
            for (int i = 0; i < 4; i++)
#pragma unroll
                for (int j = 0; j < 4; j++) acc[i][j] = fmaf(af[i], bf[j], acc[i][j]);
        }
    }
#pragma unroll
    for (int i = 0; i < 4; i++)
#pragma unroll
        for (int j = 0; j < 4; j++) {
            size_t idx = (size_t)(m0 + tm + i) * CP + n0 + tn + j;
            if (MODE == 0) out32[idx] = acc[i][j];
            else           oA[idx] = (_Float16)(acc[i][j] * 0.2f * 64.f);  // a*64
        }
}

// ---------------- MFMA bf16 GEMMs (verified layouts) ----------------
// A-frag: A[m=lane&15][k=(lane>>4)*8+j]; B-frag mirrored; C/D: col=lane&15, row=(lane>>4)*4+reg.

// GEMM1: Qf += V @ Dp over a K-chunk of CP (split-K via fp32 atomicAdd).
// V built on the fly (fp32) then split to bf16 TRIPLE; B = Dp bf16 PAIR (exact).
// MODE 0: v = a + ((P>thr)? P-2thr : -P); MODE 1: v = relu(P-thr)
template <int MODE>
__global__ __launch_bounds__(256) void kg1(const _Float16* __restrict__ AH,
                                           const float* __restrict__ Pst,
                                           const u16* __restrict__ D0p,
                                           const u16* __restrict__ D1p,
                                           float* __restrict__ Qf) {
    __shared__ u16 sA[3][128 * 32];
    __shared__ u16 sB[2][128 * 32];
    const int tid = threadIdx.x;
    const int n0 = blockIdx.x * 128;   // over DM
    const int m0 = blockIdx.y * 128;   // over BDIM
    const int ks = blockIdx.z;
    const int lane = tid & 63;
    const int wvu = tid >> 6;
    const int wm = (wvu >> 1) * 64, wn = (wvu & 1) * 64;
    const int arow = tid >> 1;         // 0..127
    const int aq = (tid & 1) * 16;     // 0 or 16
    f32x4 acc[4][4] = {};

    const int steps = CP / 32;                    // 316
    const int per = (steps + KSPL - 1) / KSPL;    // 40
    int s0 = ks * per, s1 = s0 + per;
    if (s1 > steps) s1 = steps;

    for (int sp = s0; sp < s1; ++sp) {
        const int k0 = sp * 32;
        __syncthreads();
        {   // B staging: Dp pair [512][CP]
            size_t go = (size_t)(n0 + arow) * CP + k0 + aq;
            int lb = arow * 32 + aq;
            *(u16x8*)&sB[0][lb]     = *(const u16x8*)(D0p + go);
            *(u16x8*)&sB[0][lb + 8] = *(const u16x8*)(D0p + go + 8);
            *(u16x8*)&sB[1][lb]     = *(const u16x8*)(D1p + go);
            *(u16x8*)&sB[1][lb + 8] = *(const u16x8*)(D1p + go + 8);
        }
        {   // A build: V triple
            size_t go = (size_t)(m0 + arow) * CP + k0 + aq;
            float pv[16];
            *(float4*)&pv[0]  = *(const float4*)(Pst + go);
            *(float4*)&pv[4]  = *(const float4*)(Pst + go + 4);
            *(float4*)&pv[8]  = *(const float4*)(Pst + go + 8);
            *(float4*)&pv[12] = *(const float4*)(Pst + go + 12);
            _Float16 av[16];
            if (MODE == 0) {
                *(f16x8*)&av[0] = *(const f16x8*)(AH + go);
                *(f16x8*)&av[8] = *(const f16x8*)(AH + go + 8);
            }
            u16 t0[16], t1[16], t2[16];
#pragma unroll
            for (int e = 0; e < 16; ++e) {
                float p = pv[e];
                float v;
                if (MODE == 0) {
                    float a = (float)av[e] * 0.015625f;   // /64
                    v = a + ((p > THRC) ? p - 2.f * THRC : -p);
                } else {
                    v = fmaxf(p - THRC, 0.f);
                }
                u16 h0 = f2bf(v);
                float r = v - bf2f(h0);
                u16 h1 = f2bf(r);
                t0[e] = h0; t1[e] = h1; t2[e] = f2bf(r - bf2f(h1));
            }
            int lb = arow * 32 + aq;
            *(u16x8*)&sA[0][lb]     = *(u16x8*)&t0[0];
            *(u16x8*)&sA[0][lb + 8] = *(u16x8*)&t0[8];
            *(u16x8*)&sA[1][lb]     = *(u16x8*)&t1[0];
            *(u16x8*)&sA[1][lb + 8] = *(u16x8*)&t1[8];
            *(u16x8*)&sA[2][lb]     = *(u16x8*)&t2[0];
            *(u16x8*)&sA[2][lb + 8] = *(u16x8*)&t2[8];
        }
        __syncthreads();
        s16x8 af[3][4], bf[2][4];
#pragma unroll
        for (int i = 0; i < 4; i++) {
            int ro = (wm + i * 16 + (lane & 15)) * 32 + (lane >> 4) * 8;
            af[0][i] = *(const s16x8*)&sA[0][ro];
            af[1][i] = *(const s16x8*)&sA[1][ro];
            af[2][i] = *(const s16x8*)&sA[2][ro];
        }
#pragma unroll
        for (int j = 0; j < 4; j++) {
            int ro = (wn + j * 16 + (lane & 15)) * 32 + (lane >> 4) * 8;
            bf[0][j] = *(const s16x8*)&sB[0][ro];
            bf[1][j] = *(const s16x8*)&sB[1][ro];
        }
#pragma unroll
        for (int i = 0; i < 4; i++)
#pragma unroll
            for (int j = 0; j < 4; j++) {
                acc[i][j] = __builtin_amdgcn_mfma_f32_16x16x32_bf16(af[0][i], bf[0][j], acc[i][j], 0, 0, 0);
                acc[i][j] = __builtin_amdgcn_mfma_f32_16x16x32_bf16(af[0][i], bf[1][j], acc[i][j], 0, 0, 0);
                acc[i][j] = __builtin_amdgcn_mfma_f32_16x16x32_bf16(af[1][i], bf[0][j], acc[i][j], 0, 0, 0);
                acc[i][j] = __builtin_amdgcn_mfma_f32_16x16x32_bf16(af[1][i], bf[1][j], acc[i][j], 0, 0, 0);
                acc[i][j] = __builtin_amdgcn_mfma_f32_16x16x32_bf16(af[2][i], bf[0][j], acc[i][j], 0, 0, 0);
            }
    }
    const int r0 = (lane >> 4) * 4, c0l = lane & 15;
#pragma unroll
    for (int i = 0; i < 4; i++)
#pragma unroll
        for (int v = 0; v < 4; v++) {
            int row = m0 + wm + i * 16 + r0 + v;
#pragma unroll
            for (int j = 0; j < 4; j++)
                atomicAdd(&Qf[(size_t)row * DM + n0 + wn + j * 16 + c0l], acc[i][j][v]);
        }
}

// split Q (fp32) -> bf16 triple
__global__ void kredQ(const float* __restrict__ Qf,
                      u16* __restrict__ q0, u16* __restrict__ q1, u16* __restrict__ q2) {
    size_t b = ((size_t)blockIdx.x * 256 + threadIdx.x) * 4;
    float4 s = *(const float4*)(Qf + b);
    float sv[4] = {s.x, s.y, s.z, s.w};
    u16x4 v0, v1, v2;
#pragma unroll
    for (int e = 0; e < 4; e++) {
        u16 h0 = f2bf(sv[e]);
        float r = sv[e] - bf2f(h0);
        u16 h1 = f2bf(r);
        v0[e] = h0; v1[e] = h1; v2[e] = f2bf(r - bf2f(h1));
    }
    *(u16x4*)(q0 + b) = v0;
    *(u16x4*)(q1 + b) = v1;
    *(u16x4*)(q2 + b) = v2;
}

// GEMM2: acc = Q @ E^T (out [1024][CP], K=512), fused ADMM epilogue (fp32 state):
//   P_new = a + relu(P_old - thr) - acc
__global__ __launch_bounds__(256) void kg2(const u16* __restrict__ q0,
                                           const u16* __restrict__ q1,
                                           const u16* __restrict__ q2,
                                           const u16* __restrict__ E0p,
                                           const u16* __restrict__ E1p,
                                           const u16* __restrict__ E2p,
                                           const _Float16* __restrict__ AH,
                                           float* __restrict__ Pst) {
    __shared__ u16 sA[3][128 * 32];
    __shared__ u16 sB[3][128 * 32];
    const int tid = threadIdx.x;
    const int n0 = blockIdx.x * 128;   // over CP
    const int m0 = blockIdx.y * 128;   // over BDIM
    const int lane = tid & 63;
    const int wvu = tid >> 6;
    const int wm = (wvu >> 1) * 64, wn = (wvu & 1) * 64;
    const int arow = tid >> 1;
    const int aq = (tid & 1) * 16;
    f32x4 acc[4][4] = {};

    for (int kk = 0; kk < DM / 32; ++kk) {
        const int k0 = kk * 32;
        __syncthreads();
        {   // A: Q triple [1024][512]
            size_t go = (size_t)(m0 + arow) * DM + k0 + aq;
            int lb = arow * 32 + aq;
            *(u16x8*)&sA[0][lb]     = *(const u16x8*)(q0 + go);
            *(u16x8*)&sA[0][lb + 8] = *(const u16x8*)(q0 + go + 8);
            *(u16x8*)&sA[1][lb]     = *(const u16x8*)(q1 + go);
            *(u16x8*)&sA[1][lb + 8] = *(const u16x8*)(q1 + go + 8);
            *(u16x8*)&sA[2][lb]     = *(const u16x8*)(q2 + go);
            *(u16x8*)&sA[2][lb + 8] = *(const u16x8*)(q2 + go + 8);
        }
        {   // B: E triple [CP][512]
            size_t go = (size_t)(n0 + arow) * DM + k0 + aq;
            int lb = arow * 32 + aq;
            *(u16x8*)&sB[0][lb]     = *(const u16x8*)(E0p + go);
            *(u16x8*)&sB[0][lb + 8] = *(const u16x8*)(E0p + go + 8);
            *(u16x8*)&sB[1][lb]     = *(const u16x8*)(E1p + go);
            *(u16x8*)&sB[1][lb + 8] = *(const u16x8*)(E1p + go + 8);
            *(u16x8*)&sB[2][lb]     = *(const u16x8*)(E2p + go);
            *(u16x8*)&sB[2][lb + 8] = *(const u16x8*)(E2p + go + 8);
        }
        __syncthreads();
        s16x8 af[3][4], bf[3][4];
#pragma unroll
        for (int i = 0; i < 4; i++) {
            int ro = (wm + i * 16 + (lane & 15)) * 32 + (lane >> 4) * 8;
            af[0][i] = *(const s16x8*)&sA[0][ro];
            af[1][i] = *(const s16x8*)&sA[1][ro];
            af[2][i] = *(const s16x8*)&sA[2][ro];
        }
#pragma unroll
        for (int j = 0; j < 4; j++) {
            int ro = (wn + j * 16 + (lane & 15)) * 32 + (lane >> 4) * 8;
            bf[0][j] = *(const s16x8*)&sB[0][ro];
            bf[1][j] = *(const s16x8*)&sB[1][ro];
            bf[2][j] = *(const s16x8*)&sB[2][ro];
        }
#pragma unroll
        for (int i = 0; i < 4; i++)
#pragma unroll
            for (int j = 0; j < 4; j++) {
                acc[i][j] = __builtin_amdgcn_mfma_f32_16x16x32_bf16(af[0][i], bf[0][j], acc[i][j], 0, 0, 0);
                acc[i][j] = __builtin_amdgcn_mfma_f32_16x16x32_bf16(af[0][i], bf[1][j], acc[i][j], 0, 0, 0);
                acc[i][j] = __builtin_amdgcn_mfma_f32_16x16x32_bf16(af[1][i], bf[0][j], acc[i][j], 0, 0, 0);
                acc[i][j] = __builtin_amdgcn_mfma_f32_16x16x32_bf16(af[0][i], bf[2][j], acc[i][j], 0, 0, 0);
                acc[i][j] = __builtin_amdgcn_mfma_f32_16x16x32_bf16(af[1][i], bf[1][j], acc[i][j], 0, 0, 0);
                acc[i][j] = __builtin_amdgcn_mfma_f32_16x16x32_bf16(af[2][i], bf[0][j], acc[i][j], 0, 0, 0);
            }
    }
    const int r0 = (lane >> 4) * 4, c0l = lane & 15;
#pragma unroll
    for (int i = 0; i < 4; i++)
#pragma unroll
        for (int v = 0; v < 4; v++) {
            int row = m0 + wm + i * 16 + r0 + v;
#pragma unroll
            for (int j = 0; j < 4; j++) {
                size_t idx = (size_t)row * CP + n0 + wn + j * 16 + c0l;
                float a = (float)AH[idx] * 0.015625f;
                float po = Pst[idx];
                Pst[idx] = a + fmaxf(po - THRC, 0.f) - acc[i][j][v];
            }
        }
}

// final: recon = normalize(normalize(Qf) + mean)
__global__ __launch_bounds__(256) void kfinal(const float* __restrict__ Qf,
                                              const float* __restrict__ mean,
                                              float* __restrict__ out) {
    int row = blockIdx.x, t = threadIdx.x;
    int off = row * DM + t * 2;
    float2 q = *(const float2*)(Qf + off);
    float rx = q.x, ry = q.y;
    float ss = blk_sum256(rx * rx + ry * ry);
    float inv = 1.0f / fmaxf(sqrtf(ss), 1e-12f);
    rx *= inv; ry *= inv;
    float2 mm = *(const float2*)(mean + t * 2);
    rx += mm.x; ry += mm.y;
    float ss2 = blk_sum256(rx * rx + ry * ry);
    float inv2 = 1.0f / fmaxf(sqrtf(ss2), 1e-12f);
    float2 o = {rx * inv2, ry * inv2};
    *(float2*)(out + off) = o;
}

extern "C" void kernel_launch(void* const* d_in, const int* in_sizes, int n_in,
                              void* d_out, int out_size, void* d_ws, size_t ws_size,
                              hipStream_t stream) {
    const float* image = (const float*)d_in[0];
    const float* text  = (const float*)d_in[1];
    const float* mean  = (const float*)d_in[2];
    const float* D     = (const float*)d_in[3];
    float* out = (float*)d_out;
    float* ws = (float*)d_ws;

    // ---- workspace layout (float offsets); total ~30.05M floats = 120.2 MB ----
    const size_t PL = (size_t)DM * CP / 2;     // one [512][CP] bf16 plane, in float units
    float* Y    = ws;                          // 524288 floats (loop-time: Qf)
    float* G    = ws + 524288;                 // 262144 floats (loop-time: q0/q1/q2 span G..Tns-1)
    float* Xa   = G + 262144;                  // 262144
    float* Xb   = Xa + 262144;                 // 262144
    float* Tns  = Xb + 262144;                 // 262144
    u16* D0p = (u16*)(Tns + 262144);           // 5 bf16 planes follow
    u16* D1p = (u16*)((float*)D0p + PL);
    u16* E0p = (u16*)((float*)D1p + PL);
    u16* E1p = (u16*)((float*)E0p + PL);
    u16* E2p = (u16*)((float*)E1p + PL);
    _Float16* AH = (_Float16*)((float*)E2p + PL);      // a*64 fp16 [1024][CP]
    float* P    = (float*)AH + (size_t)BDIM * CP / 2;  // fp32 [1024][CP]
    float* gmax = P + (size_t)BDIM * CP;
    // setup-only aliases (regions free at that time):
    float* Dt32 = P;                           // fp32 [512][CP] fits inside P region
    float* Et32 = (float*)AH;                  // fp32 [512][CP] == AH region size
    // loop-time aliases:
    float* Qf = Y;                             // fp32 [1024][512]
    u16* q0 = (u16*)G;
    u16* q1 = q0 + (size_t)BDIM * DM;
    u16* q2 = q1 + (size_t)BDIM * DM;

    // --- setup ---
    knorm_rows<<<BDIM, 256, 0, stream>>>(text, out + (size_t)BDIM * DM);
    kprep_Y<<<BDIM, 256, 0, stream>>>(image, mean, Y);
    // Dp: transpose D, zero-pad to CP; bf16 pair planes + pair-reconstructed fp32
    ktrs<<<dim3(CP / 64, DM / 64), 256, 0, stream>>>(D, Dt32, D0p, D1p, nullptr, CREAL, DM, CP);
    // G = Dp Dp^T + rho I ; Ginv via Newton-Schulz
    kG<<<dim3(8, 8), 256, 0, stream>>>(Dt32, G);
    (void)hipMemsetAsync(gmax, 0, 4, stream);
    krow_abssum<<<DM, 64, 0, stream>>>(G, gmax);
    kinit_X0<<<DM * DM / 256, 256, 0, stream>>>(gmax, Xa);
    float* xc = Xa;
    float* xn = Xb;
    for (int it = 0; it < NSIT; ++it) {
        kgemm_ns_T<<<dim3(8, 8), 256, 0, stream>>>(G, xc, Tns);
        kgemm_ns_X<<<dim3(8, 8), 256, 0, stream>>>(xc, Tns, xn);
        float* tmp = xc; xc = xn; xn = tmp;
    }
    float* Ginv = xc;
    // Et32 = Ginv @ Dp ; E triple = transpose-split -> [CP][512]
    kgemm_nn64<0><<<dim3(CP / 64, DM / 64), 256, 0, stream>>>(Ginv, Dt32, Et32, nullptr);
    ktrs<<<dim3(DM / 64, CP / 64), 256, 0, stream>>>(Et32, nullptr, E0p, E1p, E2p, DM, CP, DM);
    // a = (Y @ Dp)/rho stored as fp16*64 (overwrites Et32 alias - already consumed)
    kgemm_nn64<1><<<dim3(CP / 64, BDIM / 64), 256, 0, stream>>>(Y, Dt32, nullptr, AH);
    // P = 0 (kills Dt32 alias - last consumed just above)
    (void)hipMemsetAsync(P, 0, (size_t)BDIM * CP * sizeof(float), stream);

    // --- ADMM main loop ---
    for (int it = 0; it < NIT; ++it) {
        (void)hipMemsetAsync(Qf, 0, (size_t)BDIM * DM * sizeof(float), stream);
        kg1<0><<<dim3(DM / 128, BDIM / 128, KSPL), 256, 0, stream>>>(AH, P, D0p, D1p, Qf);
        kredQ<<<BDIM * DM / 1024, 256, 0, stream>>>(Qf, q0, q1, q2);
        kg2<<<dim3(CP / 128, BDIM / 128), 256, 0, stream>>>(q0, q1, q2, E0p, E1p, E2p, AH, P);
    }

    // --- finalize: recon = normalize(normalize(z @ Dp) + mean) ---
    (void)hipMemsetAsync(Qf, 0, (size_t)BDIM * DM * sizeof(float), stream);
    kg1<1><<<dim3(DM / 128, BDIM / 128, KSPL), 256, 0, stream>>>(AH, P, D0p, D1p, Qf);
    kfinal<<<BDIM, 256, 0, stream>>>(Qf, mean, out);
}

// Round 7
// 15002.002 us; speedup vs baseline: 3.1986x; 1.4452x over previous
//
#include <hip/hip_runtime.h>
#include <cstddef>
#include <cstdint>

// Problem constants
#define BDIM  1024        // batch rows
#define DM    512         // embedding dim
#define CREAL 10000       // dictionary atoms
#define CP    10112       // padded atoms = 79*128 = 158*64 = 316*32
#define KSPL  16          // split-K chunks for GEMM1 (atomic accumulation)
#define RHOC  5.0f
#define THRC  (0.01f/5.0f)
#define NIT   100
#define NSIT  12

typedef float f32x4 __attribute__((ext_vector_type(4)));
typedef _Float16 f16x8 __attribute__((ext_vector_type(8)));

// ---------------- helpers ----------------

// Split scheme: x ~ h + l/64, h = fp16(x), l = fp16((x-h)*64)  (pair error ~2^-24 rel).
// GEMM terms: h*h + (h*2^-6)*l_B + l_A*(h*2^-6)  — dropped l*l term ~2^-24 rel.
__device__ __forceinline__ f16x8 scl6(f16x8 v) {
    f16x8 r;
#pragma unroll
    for (int i = 0; i < 8; i++) r[i] = v[i] * (_Float16)0.015625f;  // exact exponent shift
    return r;
}

__device__ __forceinline__ float blk_sum256(float v) {
    __shared__ float sb[4];
#pragma unroll
    for (int o = 32; o; o >>= 1) v += __shfl_down(v, o, 64);
    int lane = threadIdx.x & 63, w = threadIdx.x >> 6;
    __syncthreads();
    if (lane == 0) sb[w] = v;
    __syncthreads();
    return sb[0] + sb[1] + sb[2] + sb[3];
}

// txt = normalize(text) per row
__global__ __launch_bounds__(256) void knorm_rows(const float* __restrict__ X,
                                                  float* __restrict__ out) {
    int row = blockIdx.x, t = threadIdx.x;
    int off = row * DM + t * 2;
    float2 v = *(const float2*)(X + off);
    float ss = blk_sum256(v.x * v.x + v.y * v.y);
    float inv = 1.0f / fmaxf(sqrtf(ss), 1e-12f);
    float2 o = {v.x * inv, v.y * inv};
    *(float2*)(out + off) = o;
}

// Y = normalize(normalize(image) - mean) per row
__global__ __launch_bounds__(256) void kprep_Y(const float* __restrict__ img,
                                               const float* __restrict__ mean,
                                               float* __restrict__ Y) {
    int row = blockIdx.x, t = threadIdx.x;
    int off = row * DM + t * 2;
    float2 v = *(const float2*)(img + off);
    float ss = blk_sum256(v.x * v.x + v.y * v.y);
    float inv = 1.0f / fmaxf(sqrtf(ss), 1e-12f);
    float2 mm = *(const float2*)(mean + t * 2);
    float tx = v.x * inv - mm.x, ty = v.y * inv - mm.y;
    float ss2 = blk_sum256(tx * tx + ty * ty);
    float inv2 = 1.0f / fmaxf(sqrtf(ss2), 1e-12f);
    float2 o = {tx * inv2, ty * inv2};
    *(float2*)(Y + off) = o;
}

// transpose (+zero-pad rows>=Rvalid), split to fp16 h/l pair (l stored *64).
// optional fp32 out = reconstructed pair (h + l/64, fp32-exact) for consistency.
__global__ __launch_bounds__(256) void ktrs(const float* __restrict__ in,
                                            float* __restrict__ out32,
                                            _Float16* __restrict__ oH,
                                            _Float16* __restrict__ oL,
                                            int Rvalid, int Cin, int Rout) {
    __shared__ float tile[64][65];
    int r0 = blockIdx.x * 64;   // rows of in  (cols of out)
    int c0 = blockIdx.y * 64;   // cols of in  (rows of out)
    int t = threadIdx.x;
    int ri = r0 + (t >> 2);
    int cc = (t & 3) * 16;
#pragma unroll
    for (int q = 0; q < 4; ++q) {
        float4 v = {0.f, 0.f, 0.f, 0.f};
        if (ri < Rvalid) v = *(const float4*)(in + (size_t)ri * Cin + c0 + cc + q * 4);
        *(float4*)&tile[t >> 2][cc + q * 4] = v;
    }
    __syncthreads();
    int oc = c0 + (t >> 2);            // out row
    int orr = r0 + (t & 3) * 16;       // out col base
#pragma unroll
    for (int q = 0; q < 16; ++q) {
        float v = tile[(t & 3) * 16 + q][t >> 2];
        size_t idx = (size_t)oc * Rout + orr + q;
        _Float16 h = (_Float16)v;
        _Float16 l = (_Float16)((v - (float)h) * 64.f);
        oH[idx] = h;
        oL[idx] = l;
        if (out32) out32[idx] = (float)h + (float)l * 0.015625f;
    }
}

// G = Dt*Dt^T + rho I  (Dt [512][CP] fp32; 64x64 tiles, K=CP)
__global__ __launch_bounds__(256) void kG(const float* __restrict__ Dt,
                                          float* __restrict__ G) {
    __shared__ float As[32][68];
    __shared__ float Bs[32][68];
    int tid = threadIdx.x;
    int j0 = blockIdx.x * 64, i0 = blockIdx.y * 64;
    int tn = (tid & 15) * 4, tm = (tid >> 4) * 4;
    float acc[4][4];
#pragma unroll
    for (int i = 0; i < 4; i++)
#pragma unroll
        for (int j = 0; j < 4; j++) acc[i][j] = 0.f;
    for (int k0 = 0; k0 < CP; k0 += 32) {
        __syncthreads();
#pragma unroll
        for (int p = 0; p < 2; ++p) {
            int idx = tid + p * 256;
            int row = idx >> 3, kv = (idx & 7) << 2;
            float4 va = *(const float4*)(Dt + (size_t)(i0 + row) * CP + k0 + kv);
            As[kv + 0][row] = va.x; As[kv + 1][row] = va.y;
            As[kv + 2][row] = va.z; As[kv + 3][row] = va.w;
            float4 vb = *(const float4*)(Dt + (size_t)(j0 + row) * CP + k0 + kv);
            Bs[kv + 0][row] = vb.x; Bs[kv + 1][row] = vb.y;
            Bs[kv + 2][row] = vb.z; Bs[kv + 3][row] = vb.w;
        }
        __syncthreads();
#pragma unroll
        for (int k = 0; k < 32; ++k) {
            float4 a4 = *(const float4*)&As[k][tm];
            float4 b4 = *(const float4*)&Bs[k][tn];
            float af[4] = {a4.x, a4.y, a4.z, a4.w};
            float bf[4] = {b4.x, b4.y, b4.z, b4.w};
#pragma unroll
            for (int i = 0; i < 4; i++)
#pragma unroll
                for (int j = 0; j < 4; j++) acc[i][j] = fmaf(af[i], bf[j], acc[i][j]);
        }
    }
#pragma unroll
    for (int i = 0; i < 4; i++)
#pragma unroll
        for (int j = 0; j < 4; j++) {
            int gi = i0 + tm + i, gj = j0 + tn + j;
            G[gi * DM + gj] = acc[i][j] + ((gi == gj) ? RHOC : 0.f);
        }
}

__global__ void krow_abssum(const float* __restrict__ G, float* __restrict__ gmax) {
    int row = blockIdx.x, t = threadIdx.x;   // 64 threads = 1 wave
    float s = 0.f;
    for (int j = t; j < DM; j += 64) s += fabsf(G[row * DM + j]);
#pragma unroll
    for (int o = 32; o; o >>= 1) s += __shfl_down(s, o, 64);
    if (t == 0) atomicMax((int*)gmax, __float_as_int(s));
}

__global__ void kinit_X0(const float* __restrict__ gmax, float* __restrict__ X) {
    int idx = blockIdx.x * 256 + threadIdx.x;
    int i = idx >> 9, j = idx & 511;
    X[idx] = (i == j) ? (1.0f / gmax[0]) : 0.0f;
}

// T = G @ X (512^3 NN, 64x64 tiles)
__global__ __launch_bounds__(256) void kgemm_ns_T(const float* __restrict__ G,
                                                  const float* __restrict__ X,
                                                  float* __restrict__ T) {
    __shared__ float As[32][68];
    __shared__ float Bs[32][68];
    int tid = threadIdx.x;
    int n0 = blockIdx.x * 64, m0 = blockIdx.y * 64;
    int tn = (tid & 15) * 4, tm = (tid >> 4) * 4;
    float acc[4][4];
#pragma unroll
    for (int i = 0; i < 4; i++)
#pragma unroll
        for (int j = 0; j < 4; j++) acc[i][j] = 0.f;
    for (int k0 = 0; k0 < DM; k0 += 32) {
        __syncthreads();
#pragma unroll
        for (int p = 0; p < 2; ++p) {
            int idx = tid + p * 256;
            {
                int row = idx >> 3, kv = (idx & 7) << 2;
                float4 v = *(const float4*)(G + (m0 + row) * DM + k0 + kv);
                As[kv + 0][row] = v.x; As[kv + 1][row] = v.y;
                As[kv + 2][row] = v.z; As[kv + 3][row] = v.w;
            }
            {
                int r = idx >> 4, cv = (idx & 15) << 2;
                *(float4*)&Bs[r][cv] = *(const float4*)(X + (k0 + r) * DM + n0 + cv);
            }
        }
        __syncthreads();
#pragma unroll
        for (int k = 0; k < 32; ++k) {
            float4 a4 = *(const float4*)&As[k][tm];
            float4 b4 = *(const float4*)&Bs[k][tn];
            float af[4] = {a4.x, a4.y, a4.z, a4.w};
            float bf[4] = {b4.x, b4.y, b4.z, b4.w};
#pragma unroll
            for (int i = 0; i < 4; i++)
#pragma unroll
                for (int j = 0; j < 4; j++) acc[i][j] = fmaf(af[i], bf[j], acc[i][j]);
        }
    }
#pragma unroll
    for (int i = 0; i < 4; i++) {
        float4 o = {acc[i][0], acc[i][1], acc[i][2], acc[i][3]};
        *(float4*)(T + (m0 + tm + i) * DM + n0 + tn) = o;
    }
}

// Xn = 2*Xo - Xo @ T
__global__ __launch_bounds__(256) void kgemm_ns_X(const float* __restrict__ Xo,
                                                  const float* __restrict__ T,
                                                  float* __restrict__ Xn) {
    __shared__ float As[32][68];
    __shared__ float Bs[32][68];
    int tid = threadIdx.x;
    int n0 = blockIdx.x * 64, m0 = blockIdx.y * 64;
    int tn = (tid & 15) * 4, tm = (tid >> 4) * 4;
    float acc[4][4];
#pragma unroll
    for (int i = 0; i < 4; i++)
#pragma unroll
        for (int j = 0; j < 4; j++) acc[i][j] = 0.f;
    for (int k0 = 0; k0 < DM; k0 += 32) {
        __syncthreads();
#pragma unroll
        for (int p = 0; p < 2; ++p) {
            int idx = tid + p * 256;
            {
                int row = idx >> 3, kv = (idx & 7) << 2;
                float4 v = *(const float4*)(Xo + (m0 + row) * DM + k0 + kv);
                As[kv + 0][row] = v.x; As[kv + 1][row] = v.y;
                As[kv + 2][row] = v.z; As[kv + 3][row] = v.w;
            }
            {
                int r = idx >> 4, cv = (idx & 15) << 2;
                *(float4*)&Bs[r][cv] = *(const float4*)(T + (k0 + r) * DM + n0 + cv);
            }
        }
        __syncthreads();
#pragma unroll
        for (int k = 0; k < 32; ++k) {
            float4 a4 = *(const float4*)&As[k][tm];
            float4 b4 = *(const float4*)&Bs[k][tn];
            float af[4] = {a4.x, a4.y, a4.z, a4.w};
            float bf[4] = {b4.x, b4.y, b4.z, b4.w};
#pragma unroll
            for (int i = 0; i < 4; i++)
#pragma unroll
                for (int j = 0; j < 4; j++) acc[i][j] = fmaf(af[i], bf[j], acc[i][j]);
        }
    }
#pragma unroll
    for (int i = 0; i < 4; i++) {
        int base = (m0 + tm + i) * DM + n0 + tn;
        float4 xo = *(const float4*)(Xo + base);
        float4 o = {2.f * xo.x - acc[i][0], 2.f * xo.y - acc[i][1],
                    2.f * xo.z - acc[i][2], 2.f * xo.w - acc[i][3]};
        *(float4*)(Xn + base) = o;
    }
}

// NN fp32: out[M][CP] = A[M][512] @ B[512][CP]
// MODE 0: store fp32. MODE 1: store a = acc*0.2 as fp16 scaled by 64.
template <int MODE>
__global__ __launch_bounds__(256) void kgemm_nn64(const float* __restrict__ A,
                                                  const float* __restrict__ B,
                                                  float* __restrict__ out32,
                                                  _Float16* __restrict__ oA) {
    __shared__ float As[32][68];
    __shared__ float Bs[32][68];
    int tid = threadIdx.x;
    int n0 = blockIdx.x * 64, m0 = blockIdx.y * 64;
    int tn = (tid & 15) * 4, tm = (tid >> 4) * 4;
    float acc[4][4];
#pragma unroll
    for (int i = 0; i < 4; i++)
#pragma unroll
        for (int j = 0; j < 4; j++) acc[i][j] = 0.f;
    for (int k0 = 0; k0 < DM; k0 += 32) {
        __syncthreads();
#pragma unroll
        for (int p = 0; p < 2; ++p) {
            int idx = tid + p * 256;
            {
                int row = idx >> 3, kv = (idx & 7) << 2;
                float4 v = *(const float4*)(A + (size_t)(m0 + row) * DM + k0 + kv);
                As[kv + 0][row] = v.x; As[kv + 1][row] = v.y;
                As[kv + 2][row] = v.z; As[kv + 3][row] = v.w;
            }
            {
                int r = idx >> 4, cv = (idx & 15) << 2;
                *(float4*)&Bs[r][cv] = *(const float4*)(B + (size_t)(k0 + r) * CP + n0 + cv);
            }
        }
        __syncthreads();
#pragma unroll
        for (int k = 0; k < 32; ++k) {
            float4 a4 = *(const float4*)&As[k][tm];
            float4 b4 = *(const float4*)&Bs[k][tn];
            float af[4] = {a4.x, a4.y, a4.z, a4.w};
            float bf[4] = {b4.x, b4.y, b4.z, b4.w};
#pragma unroll
            for (int i = 0; i < 4; i++)
#pragma unroll
                for (int j = 0; j < 4; j++) acc[i][j] = fmaf(af[i], bf[j], acc[i][j]);
        }
    }
#pragma unroll
    for (int i = 0; i < 4; i++)
#pragma unroll
        for (int j = 0; j < 4; j++) {
            size_t idx = (size_t)(m0 + tm + i) * CP + n0 + tn + j;
            if (MODE == 0) out32[idx] = acc[i][j];
            else           oA[idx] = (_Float16)(acc[i][j] * 0.2f * 64.f);
        }
}

// aD = Y@G/rho - Y   (out [1024][512]; 64x64 tiles, K=512)
__global__ __launch_bounds__(256) void kgemm_aD(const float* __restrict__ Yb,
                                                const float* __restrict__ G,
                                                float* __restrict__ aD) {
    __shared__ float As[32][68];
    __shared__ float Bs[32][68];
    int tid = threadIdx.x;
    int n0 = blockIdx.x * 64, m0 = blockIdx.y * 64;
    int tn = (tid & 15) * 4, tm = (tid >> 4) * 4;
    float acc[4][4];
#pragma unroll
    for (int i = 0; i < 4; i++)
#pragma unroll
        for (int j = 0; j < 4; j++) acc[i][j] = 0.f;
    for (int k0 = 0; k0 < DM; k0 += 32) {
        __syncthreads();
#pragma unroll
        for (int p = 0; p < 2; ++p) {
            int idx = tid + p * 256;
            {
                int row = idx >> 3, kv = (idx & 7) << 2;
                float4 v = *(const float4*)(Yb + (size_t)(m0 + row) * DM + k0 + kv);
                As[kv + 0][row] = v.x; As[kv + 1][row] = v.y;
                As[kv + 2][row] = v.z; As[kv + 3][row] = v.w;
            }
            {
                int r = idx >> 4, cv = (idx & 15) << 2;
                *(float4*)&Bs[r][cv] = *(const float4*)(G + (k0 + r) * DM + n0 + cv);
            }
        }
        __syncthreads();
#pragma unroll
        for (int k = 0; k < 32; ++k) {
            float4 a4 = *(const float4*)&As[k][tm];
            float4 b4 = *(const float4*)&Bs[k][tn];
            float af[4] = {a4.x, a4.y, a4.z, a4.w};
            float bf[4] = {b4.x, b4.y, b4.z, b4.w};
#pragma unroll
            for (int i = 0; i < 4; i++)
#pragma unroll
                for (int j = 0; j < 4; j++) acc[i][j] = fmaf(af[i], bf[j], acc[i][j]);
        }
    }
#pragma unroll
    for (int i = 0; i < 4; i++) {
        int base = (m0 + tm + i) * DM + n0 + tn;
        float4 y4 = *(const float4*)(Yb + base);
        float4 o = {acc[i][0] * 0.2f - y4.x, acc[i][1] * 0.2f - y4.y,
                    acc[i][2] * 0.2f - y4.z, acc[i][3] * 0.2f - y4.w};
        *(float4*)(aD + base) = o;
    }
}

// ---------------- MFMA fp16-pair GEMMs ----------------
// A-frag: A[m=lane&15][k=(lane>>4)*8+j]; B-frag mirrored; C/D: col=lane&15, row=(lane>>4)*4+reg.

// GEMM1: Qf += (z-u) @ Dp over a K-chunk of CP (split-K via fp32 atomicAdd; Qf pre-set to aD).
// MODE 0: v = (P>thr)? P-2thr : -P ;  MODE 1: v = relu(P-thr)  (final z@Dp, Qf pre-set to 0)
template <int MODE>
__global__ __launch_bounds__(256) void kg1(const float* __restrict__ Pst,
                                           const _Float16* __restrict__ DHp,
                                           const _Float16* __restrict__ DLp,
                                           float* __restrict__ Qf) {
    __shared__ _Float16 sA[2][128 * 32];
    __shared__ _Float16 sB[2][128 * 32];
    const int tid = threadIdx.x;
    const int n0 = blockIdx.x * 128;   // over DM
    const int m0 = blockIdx.y * 128;   // over BDIM
    const int ks = blockIdx.z;
    const int lane = tid & 63;
    const int wvu = tid >> 6;
    const int wm = (wvu >> 1) * 64, wn = (wvu & 1) * 64;
    const int arow = tid >> 1;         // 0..127
    const int aq = (tid & 1) * 16;     // 0 or 16
    f32x4 acc[4][4] = {};

    const int steps = CP / 32;                    // 316
    const int per = (steps + KSPL - 1) / KSPL;    // 20
    int s0 = ks * per;
    int s1 = s0 + per; if (s1 > steps) s1 = steps;

    for (int sp = s0; sp < s1; ++sp) {
        const int k0 = sp * 32;
        __syncthreads();
        {   // B staging: Dp pair [512][CP]
            size_t go = (size_t)(n0 + arow) * CP + k0 + aq;
            int lb = arow * 32 + aq;
            *(f16x8*)&sB[0][lb]     = *(const f16x8*)(DHp + go);
            *(f16x8*)&sB[0][lb + 8] = *(const f16x8*)(DHp + go + 8);
            *(f16x8*)&sB[1][lb]     = *(const f16x8*)(DLp + go);
            *(f16x8*)&sB[1][lb + 8] = *(const f16x8*)(DLp + go + 8);
        }
        {   // A build from P, split to fp16 pair
            size_t go = (size_t)(m0 + arow) * CP + k0 + aq;
            float pv[16];
            *(float4*)&pv[0]  = *(const float4*)(Pst + go);
            *(float4*)&pv[4]  = *(const float4*)(Pst + go + 4);
            *(float4*)&pv[8]  = *(const float4*)(Pst + go + 8);
            *(float4*)&pv[12] = *(const float4*)(Pst + go + 12);
            _Float16 th[16], tl[16];
#pragma unroll
            for (int e = 0; e < 16; ++e) {
                float p = pv[e];
                float v = (MODE == 0) ? ((p > THRC) ? p - 2.f * THRC : -p)
                                      : fmaxf(p - THRC, 0.f);
                _Float16 h = (_Float16)v;
                th[e] = h;
                tl[e] = (_Float16)((v - (float)h) * 64.f);
            }
            int lb = arow * 32 + aq;
            *(f16x8*)&sA[0][lb]     = *(f16x8*)&th[0];
            *(f16x8*)&sA[0][lb + 8] = *(f16x8*)&th[8];
            *(f16x8*)&sA[1][lb]     = *(f16x8*)&tl[0];
            *(f16x8*)&sA[1][lb + 8] = *(f16x8*)&tl[8];
        }
        __syncthreads();
        f16x8 af[2][4], bf[2][4], afs[4], bfs[4];
#pragma unroll
        for (int i = 0; i < 4; i++) {
            int ro = (wm + i * 16 + (lane & 15)) * 32 + (lane >> 4) * 8;
            af[0][i] = *(const f16x8*)&sA[0][ro];
            af[1][i] = *(const f16x8*)&sA[1][ro];
            afs[i] = scl6(af[0][i]);
        }
#pragma unroll
        for (int j = 0; j < 4; j++) {
            int ro = (wn + j * 16 + (lane & 15)) * 32 + (lane >> 4) * 8;
            bf[0][j] = *(const f16x8*)&sB[0][ro];
            bf[1][j] = *(const f16x8*)&sB[1][ro];
            bfs[j] = scl6(bf[0][j]);
        }
#pragma unroll
        for (int i = 0; i < 4; i++)
#pragma unroll
            for (int j = 0; j < 4; j++) {
                acc[i][j] = __builtin_amdgcn_mfma_f32_16x16x32_f16(af[0][i], bf[0][j], acc[i][j], 0, 0, 0);
                acc[i][j] = __builtin_amdgcn_mfma_f32_16x16x32_f16(afs[i],   bf[1][j], acc[i][j], 0, 0, 0);
                acc[i][j] = __builtin_amdgcn_mfma_f32_16x16x32_f16(af[1][i], bfs[j],   acc[i][j], 0, 0, 0);
            }
    }
    const int r0 = (lane >> 4) * 4, c0l = lane & 15;
#pragma unroll
    for (int i = 0; i < 4; i++)
#pragma unroll
        for (int v = 0; v < 4; v++) {
            int row = m0 + wm + i * 16 + r0 + v;
#pragma unroll
            for (int j = 0; j < 4; j++)
                atomicAdd(&Qf[(size_t)row * DM + n0 + wn + j * 16 + c0l], acc[i][j][v]);
        }
}

// GEMM2: acc = Q @ E^T (out [1024][CP], K=512), fused ADMM epilogue (fp32 state):
//   P_new = a + relu(P_old - thr) - acc.  A built in-kernel from fp32 Qf (pair split).
__global__ __launch_bounds__(256) void kg2(const float* __restrict__ Qf,
                                           const _Float16* __restrict__ EHp,
                                           const _Float16* __restrict__ ELp,
                                           const _Float16* __restrict__ AH,
                                           float* __restrict__ Pst) {
    __shared__ _Float16 sA[2][128 * 32];
    __shared__ _Float16 sB[2][128 * 32];
    const int tid = threadIdx.x;
    const int n0 = blockIdx.x * 128;   // over CP
    const int m0 = blockIdx.y * 128;   // over BDIM
    const int lane = tid & 63;
    const int wvu = tid >> 6;
    const int wm = (wvu >> 1) * 64, wn = (wvu & 1) * 64;
    const int arow = tid >> 1;
    const int aq = (tid & 1) * 16;
    f32x4 acc[4][4] = {};

    for (int kk = 0; kk < DM / 32; ++kk) {
        const int k0 = kk * 32;
        __syncthreads();
        {   // B: E pair [CP][512]
            size_t go = (size_t)(n0 + arow) * DM + k0 + aq;
            int lb = arow * 32 + aq;
            *(f16x8*)&sB[0][lb]     = *(const f16x8*)(EHp + go);
            *(f16x8*)&sB[0][lb + 8] = *(const f16x8*)(EHp + go + 8);
            *(f16x8*)&sB[1][lb]     = *(const f16x8*)(ELp + go);
            *(f16x8*)&sB[1][lb + 8] = *(const f16x8*)(ELp + go + 8);
        }
        {   // A build from fp32 Qf, split to fp16 pair
            size_t go = (size_t)(m0 + arow) * DM + k0 + aq;
            float qv[16];
            *(float4*)&qv[0]  = *(const float4*)(Qf + go);
            *(float4*)&qv[4]  = *(const float4*)(Qf + go + 4);
            *(float4*)&qv[8]  = *(const float4*)(Qf + go + 8);
            *(float4*)&qv[12] = *(const float4*)(Qf + go + 12);
            _Float16 th[16], tl[16];
#pragma unroll
            for (int e = 0; e < 16; ++e) {
                float v = qv[e];
                _Float16 h = (_Float16)v;
                th[e] = h;
                tl[e] = (_Float16)((v - (float)h) * 64.f);
            }
            int lb = arow * 32 + aq;
            *(f16x8*)&sA[0][lb]     = *(f16x8*)&th[0];
            *(f16x8*)&sA[0][lb + 8] = *(f16x8*)&th[8];
            *(f16x8*)&sA[1][lb]     = *(f16x8*)&tl[0];
            *(f16x8*)&sA[1][lb + 8] = *(f16x8*)&tl[8];
        }
        __syncthreads();
        f16x8 af[2][4], bf[2][4], afs[4], bfs[4];
#pragma unroll
        for (int i = 0; i < 4; i++) {
            int ro = (wm + i * 16 + (lane & 15)) * 32 + (lane >> 4) * 8;
            af[0][i] = *(const f16x8*)&sA[0][ro];
            af[1][i] = *(const f16x8*)&sA[1][ro];
            afs[i] = scl6(af[0][i]);
        }
#pragma unroll
        for (int j = 0; j < 4; j++) {
            int ro = (wn + j * 16 + (lane & 15)) * 32 + (lane >> 4) * 8;
            bf[0][j] = *(const f16x8*)&sB[0][ro];
            bf[1][j] = *(const f16x8*)&sB[1][ro];
            bfs[j] = scl6(bf[0][j]);
        }
#pragma unroll
        for (int i = 0; i < 4; i++)
#pragma unroll
            for (int j = 0; j < 4; j++) {
                acc[i][j] = __builtin_amdgcn_mfma_f32_16x16x32_f16(af[0][i], bf[0][j], acc[i][j], 0, 0, 0);
                acc[i][j] = __builtin_amdgcn_mfma_f32_16x16x32_f16(afs[i],   bf[1][j], acc[i][j], 0, 0, 0);
                acc[i][j] = __builtin_amdgcn_mfma_f32_16x16x32_f16(af[1][i], bfs[j],   acc[i][j], 0, 0, 0);
            }
    }
    const int r0 = (lane >> 4) * 4, c0l = lane & 15;
#pragma unroll
    for (int i = 0; i < 4; i++)
#pragma unroll
        for (int v = 0; v < 4; v++) {
            int row = m0 + wm + i * 16 + r0 + v;
#pragma unroll
            for (int j = 0; j < 4; j++) {
                size_t idx = (size_t)row * CP + n0 + wn + j * 16 + c0l;
                float a = (float)AH[idx] * 0.015625f;
                float po = Pst[idx];
                Pst[idx] = a + fmaxf(po - THRC, 0.f) - acc[i][j][v];
            }
        }
}

// final: recon = normalize(normalize(Qf) + mean)
__global__ __launch_bounds__(256) void kfinal(const float* __restrict__ Qf,
                                              const float* __restrict__ mean,
                                              float* __restrict__ out) {
    int row = blockIdx.x, t = threadIdx.x;
    int off = row * DM + t * 2;
    float2 q = *(const float2*)(Qf + off);
    float rx = q.x, ry = q.y;
    float ss = blk_sum256(rx * rx + ry * ry);
    float inv = 1.0f / fmaxf(sqrtf(ss), 1e-12f);
    rx *= inv; ry *= inv;
    float2 mm = *(const float2*)(mean + t * 2);
    rx += mm.x; ry += mm.y;
    float ss2 = blk_sum256(rx * rx + ry * ry);
    float inv2 = 1.0f / fmaxf(sqrtf(ss2), 1e-12f);
    float2 o = {rx * inv2, ry * inv2};
    *(float2*)(out + off) = o;
}

extern "C" void kernel_launch(void* const* d_in, const int* in_sizes, int n_in,
                              void* d_out, int out_size, void* d_ws, size_t ws_size,
                              hipStream_t stream) {
    const float* image = (const float*)d_in[0];
    const float* text  = (const float*)d_in[1];
    const float* mean  = (const float*)d_in[2];
    const float* D     = (const float*)d_in[3];
    float* out = (float*)d_out;
    float* ws = (float*)d_ws;

    // ---- workspace layout (float offsets); total ~28.0M floats = 112 MB ----
    const size_t PL = (size_t)DM * CP / 2;     // one [512][CP] fp16 plane, in float units
    float* Y    = ws;                          // 524288 floats (loop-time: Qf)
    float* G    = ws + 524288;                 // 262144
    float* Xa   = G + 262144;                  // 262144
    float* Xb   = Xa + 262144;                 // 262144
    float* Tns  = Xb + 262144;                 // 262144
    _Float16* DHp = (_Float16*)(Tns + 262144); // 4 fp16 planes follow
    _Float16* DLp = (_Float16*)((float*)DHp + PL);
    _Float16* EHp = (_Float16*)((float*)DLp + PL);
    _Float16* ELp = (_Float16*)((float*)EHp + PL);
    _Float16* AH = (_Float16*)((float*)ELp + PL);      // a*64 fp16 [1024][CP]
    float* aD   = (float*)AH + (size_t)BDIM * CP / 2;  // fp32 [1024][512]
    float* P    = aD + (size_t)BDIM * DM;              // fp32 [1024][CP]
    float* gmax = P + (size_t)BDIM * CP;
    // setup-only aliases (regions free at that time):
    float* Dt32 = P;                           // fp32 [512][CP] fits inside P region
    float* Et32 = (float*)AH;                  // fp32 [512][CP] == AH region size
    // loop-time alias:
    float* Qf = Y;                             // fp32 [1024][512]

    // --- setup ---
    knorm_rows<<<BDIM, 256, 0, stream>>>(text, out + (size_t)BDIM * DM);
    kprep_Y<<<BDIM, 256, 0, stream>>>(image, mean, Y);
    // Dp: transpose D, zero-pad to CP; fp16 pair planes + pair-reconstructed fp32
    ktrs<<<dim3(CP / 64, DM / 64), 256, 0, stream>>>(D, Dt32, DHp, DLp, CREAL, DM, CP);
    // G = Dp Dp^T + rho I ; Ginv via Newton-Schulz
    kG<<<dim3(8, 8), 256, 0, stream>>>(Dt32, G);
    (void)hipMemsetAsync(gmax, 0, 4, stream);
    krow_abssum<<<DM, 64, 0, stream>>>(G, gmax);
    kinit_X0<<<DM * DM / 256, 256, 0, stream>>>(gmax, Xa);
    float* xc = Xa;
    float* xn = Xb;
    for (int it = 0; it < NSIT; ++it) {
        kgemm_ns_T<<<dim3(8, 8), 256, 0, stream>>>(G, xc, Tns);
        kgemm_ns_X<<<dim3(8, 8), 256, 0, stream>>>(xc, Tns, xn);
        float* tmp = xc; xc = xn; xn = tmp;
    }
    float* Ginv = xc;
    // Et32 = Ginv @ Dp ; E pair = transpose-split -> [CP][512]
    kgemm_nn64<0><<<dim3(CP / 64, DM / 64), 256, 0, stream>>>(Ginv, Dt32, Et32, nullptr);
    ktrs<<<dim3(DM / 64, CP / 64), 256, 0, stream>>>(Et32, nullptr, EHp, ELp, DM, CP, DM);
    // a = (Y @ Dp)/rho stored as fp16*64 (overwrites Et32 alias - already consumed)
    kgemm_nn64<1><<<dim3(CP / 64, BDIM / 64), 256, 0, stream>>>(Y, Dt32, nullptr, AH);
    // aD = a @ Dp^T = Y@G/rho - Y  (per-iteration Qf initializer)
    kgemm_aD<<<dim3(DM / 64, BDIM / 64), 256, 0, stream>>>(Y, G, aD);
    // P = 0 (kills Dt32 alias - last consumed just above)
    (void)hipMemsetAsync(P, 0, (size_t)BDIM * CP * sizeof(float), stream);

    // --- ADMM main loop ---
    for (int it = 0; it < NIT; ++it) {
        (void)hipMemcpyAsync(Qf, aD, (size_t)BDIM * DM * sizeof(float),
                             hipMemcpyDeviceToDevice, stream);
        kg1<0><<<dim3(DM / 128, BDIM / 128, KSPL), 256, 0, stream>>>(P, DHp, DLp, Qf);
        kg2<<<dim3(CP / 128, BDIM / 128), 256, 0, stream>>>(Qf, EHp, ELp, AH, P);
    }

    // --- finalize: recon = normalize(normalize(z @ Dp) + mean) ---
    (void)hipMemsetAsync(Qf, 0, (size_t)BDIM * DM * sizeof(float), stream);
    kg1<1><<<dim3(DM / 128, BDIM / 128, KSPL), 256, 0, stream>>>(P, DHp, DLp, Qf);
    kfinal<<<BDIM, 256, 0, stream>>>(Qf, mean, out);
}